// Round 1
// baseline (592.680 us; speedup 1.0000x reference)
//
#include <hip/hip_runtime.h>

// Patch2Im: col2im fold (k=7, stride=3) of (4,64,7,7,85,85) fp32 patches into
// a (4,64,259,259) image, normalized by overlap counts, cropped by 3 px on
// each side -> (4,64,253,253).
//
// Gather formulation: each output pixel (b,c,h,w) with padded coords
// hp=h+3, wp=w+3 sums x_patch[b,c,i,j,ph,pw] over all (ph,pw) with
// i = hp-3*ph in [0,7) and j = wp-3*pw in [0,7), then divides by the
// contribution count n_h*n_w (each in {2,3} for the cropped interior).
// Every input element is read at most once across the grid -> memory-bound,
// ~428 MB total traffic, ~68 us roofline at 6.3 TB/s.

constexpr int K   = 7;
constexpr int S   = 3;
constexpr int NH  = 85;
constexpr int NW  = 85;
constexpr int OH  = 253;   // 259 - 2*3
constexpr int OW  = 253;
constexpr int PAD = 3;

__global__ __launch_bounds__(256) void patch2im_kernel(
    const float* __restrict__ x, float* __restrict__ out, int total)
{
    int idx = blockIdx.x * 256 + threadIdx.x;
    if (idx >= total) return;

    // out layout: (B*C, OH, OW) flattened
    int w  = idx % OW;
    int t  = idx / OW;
    int h  = t % OH;
    int bc = t / OH;

    int hp = h + PAD;          // padded-image row,  in [3, 256)
    int wp = w + PAD;          // padded-image col

    // ph range: i = hp - 3*ph in [0, K) and ph in [0, NH)
    // ceil((hp-6)/3) via truncating division: hp-4 >= -1 so trunc == ceil here
    int ph_min = (hp - (K - 1) + (S - 1)) / S;  // (hp-4)/3
    if (ph_min < 0) ph_min = 0;
    int ph_max = hp / S;
    if (ph_max > NH - 1) ph_max = NH - 1;

    int pw_min = (wp - (K - 1) + (S - 1)) / S;
    if (pw_min < 0) pw_min = 0;
    int pw_max = wp / S;
    if (pw_max > NW - 1) pw_max = NW - 1;

    int nh = ph_max - ph_min + 1;   // 2 or 3
    int nw = pw_max - pw_min + 1;   // 2 or 3

    const float* base = x + (long long)bc * (K * K * NH * NW);

    float sum = 0.0f;
    #pragma unroll 3
    for (int ph = ph_min; ph <= ph_max; ++ph) {
        int i = hp - S * ph;                       // [0, K)
        const float* rowb = base + (i * K) * (NH * NW) + ph * NW;
        #pragma unroll 3
        for (int pw = pw_min; pw <= pw_max; ++pw) {
            int j = wp - S * pw;                   // [0, K)
            sum += rowb[j * (NH * NW) + pw];
        }
    }

    out[idx] = sum / (float)(nh * nw);
}

extern "C" void kernel_launch(void* const* d_in, const int* in_sizes, int n_in,
                              void* d_out, int out_size, void* d_ws, size_t ws_size,
                              hipStream_t stream) {
    const float* x = (const float*)d_in[0];
    float* out = (float*)d_out;

    int total = out_size;                       // 4*64*253*253 = 16,386,304
    int blocks = (total + 255) / 256;
    patch2im_kernel<<<blocks, 256, 0, stream>>>(x, out, total);
}

// Round 3
// 482.412 us; speedup vs baseline: 1.2286x; 1.2286x over previous
//
#include <hip/hip_runtime.h>

// Patch2Im col2im (k=7, stride=3), gather form, phase-decomposed:
// wp = 3q + r. Contributions per output:
//   r=0: j=0@pw=q, j=3@pw=q-1, j=6@pw=q-2
//   r=1: j=1@pw=q, j=4@pw=q-1
//   r=2: j=2@pw=q, j=5@pw=q-1
// One thread per (bc, h, q) produces outputs w = 3t,3t+1,3t+2 (t=q-1) with
// 7 loads per contributing ph; consecutive threads read consecutive pw in
// every plane -> fully coalesced loads. Each input element read once.

constexpr int K   = 7;
constexpr int S   = 3;
constexpr int NH  = 85;
constexpr int NW  = 85;
constexpr int OH  = 253;
constexpr int OW  = 253;
constexpr int PAD = 3;
constexpr int PLANE = NH * NW;        // 7225
constexpr int TQ  = 85;               // q-threads per output row

__global__ __launch_bounds__(256) void patch2im_kernel(
    const float* __restrict__ x, float* __restrict__ out, int total)
{
    int idx = blockIdx.x * 256 + threadIdx.x;
    if (idx >= total) return;

    int t  = idx % TQ;        // q-group; q = t+1
    int r2 = idx / TQ;
    int h  = r2 % OH;
    int bc = r2 / OH;

    int q  = t + 1;
    int hp = h + PAD;                       // [3, 256)

    // contributing ph range (rows): ph in [ceil((hp-6)/3), floor(hp/3)] ∩ [0,84]
    int ph_min = (hp >= K) ? (hp - (K - 1) + (S - 1)) / S : 0;   // (hp-4)/3
    int ph_max = hp / S;
    if (ph_max > NH - 1) ph_max = NH - 1;
    int nh = ph_max - ph_min + 1;           // 2 or 3

    const bool hasR = (q <= NW - 1);        // pw=q valid (j=0,1,2); false only t=84
    const bool hasL = (t >= 1);             // pw=q-2=t-1 valid (j=6); false only t=0

    const float* base = x + (size_t)bc * (K * K * PLANE);

    float o0 = 0.f, o1 = 0.f, o2 = 0.f;
    for (int ph = ph_min; ph <= ph_max; ++ph) {
        int i = hp - S * ph;                               // [0, K)
        const float* pb = base + (i * K) * PLANE + ph * NW; // plane (i,0), row ph
        float v3 = pb[3 * PLANE + t];                      // pw = q-1 = t
        float v4 = pb[4 * PLANE + t];
        float v5 = pb[5 * PLANE + t];
        float v0 = hasR ? pb[0 * PLANE + q] : 0.f;         // pw = q
        float v1 = hasR ? pb[1 * PLANE + q] : 0.f;
        float v2 = hasR ? pb[2 * PLANE + q] : 0.f;
        float v6 = hasL ? pb[6 * PLANE + (t - 1)] : 0.f;   // pw = q-2
        o0 += v0 + v3 + v6;
        o1 += v1 + v4;
        o2 += v2 + v5;
    }

    int nw0 = 1 + (hasR ? 1 : 0) + (hasL ? 1 : 0);  // 3 interior, 2 at edges
    float fnh = (float)nh;

    float* orow = out + ((size_t)bc * OH + h) * OW;
    int w0 = 3 * t;
    orow[w0] = o0 / (fnh * (float)nw0);
    if (t < TQ - 1) {                       // w = 253,254 don't exist for t=84
        float inv = 1.0f / (fnh * 2.0f);
        orow[w0 + 1] = o1 * inv;
        orow[w0 + 2] = o2 * inv;
    }
}

extern "C" void kernel_launch(void* const* d_in, const int* in_sizes, int n_in,
                              void* d_out, int out_size, void* d_ws, size_t ws_size,
                              hipStream_t stream) {
    const float* x = (const float*)d_in[0];
    float* out = (float*)d_out;

    int total = 256 * OH * TQ;              // bc * rows * q-threads = 5,505,280
    int blocks = (total + 255) / 256;
    patch2im_kernel<<<blocks, 256, 0, stream>>>(x, out, total);
}